// Round 8
// baseline (1741.593 us; speedup 1.0000x reference)
//
#include <hip/hip_runtime.h>
#include <hip/hip_bf16.h>

// H2Conv: Xh = lorentz_linear(X W^T + b); Xve = Xh[vertex]-emb[ty];
// Xe = segsum(Xve, edges); Xv = segsum(Xe[edges], vertex); out = eps*Xv + Xh
// N=100000, E=20000, NNZ=1e6, D=128. vertex < 2^17, type < 16.
//
// R8: GEMM back to 4x8 thread tile (R7's 8x8 spilled: VGPR=256 cap,
// 730MB scratch WRITE => 508us). Occupancy fixed via K-chunked staging:
// LDS 99KB -> 27.6KB, __launch_bounds__(256,3) => 3 blocks/CU (was 1).

#define E_SEGS 20000

// ---------------- Kernel 1: fused GEMM + lorentz epilogue -------------------
// 64 rows/block, 256 threads, K in 4 chunks of 32 floats. Thread tile 4x8.
// LDS: Ws[128][9]f4 (18.4KB, XOR-swizzled) + Xs[64][9]f4 (9.2KB, pad only).
// All LDS reads <=2-way bank conflict (free); writes conflict-free.
__global__ __launch_bounds__(256, 3) void lorentz_gemm_kernel(
    const float* __restrict__ X, const float* __restrict__ W,
    const float* __restrict__ bias, const float* __restrict__ scale_log,
    float* __restrict__ Xh, int N)
{
    __shared__ float4 Ws[128 * 9];
    __shared__ float4 Xs[64 * 9];
    const int t = threadIdx.x;
    const int row0 = blockIdx.x * 64;

    const int rg = t >> 4;           // 0..15 -> rows rg*4..+3
    const int cg = t & 15;           // 0..15 -> cols cg*8..+7
    const int sr = t >> 3;           // staging row base (0..31)
    const int sc = t & 7;            // staging f4 col within chunk

    float acc[4][8];
    #pragma unroll
    for (int r = 0; r < 4; ++r)
        #pragma unroll
        for (int j = 0; j < 8; ++j) acc[r][j] = 0.f;

    for (int ch = 0; ch < 4; ++ch) {
        if (ch) __syncthreads();
        const int kb = ch * 8;       // f4 offset of this K-chunk
        #pragma unroll
        for (int i = 0; i < 4; ++i) {
            int d = sr + i * 32;     // W row 0..127
            Ws[d * 9 + (sc ^ ((d >> 3) & 7))] =
                ((const float4*)W)[(size_t)d * 32 + kb + sc];
        }
        #pragma unroll
        for (int i = 0; i < 2; ++i) {
            int r = sr + i * 32;     // tile row 0..63
            int gr = row0 + r;
            float4 x = make_float4(0.f, 0.f, 0.f, 0.f);
            if (gr < N) x = ((const float4*)X)[(size_t)gr * 32 + kb + sc];
            Xs[r * 9 + sc] = x;
        }
        __syncthreads();

        #pragma unroll
        for (int k4 = 0; k4 < 8; ++k4) {
            float4 xq[4];
            #pragma unroll
            for (int rr = 0; rr < 4; ++rr)
                xq[rr] = Xs[(rg * 4 + rr) * 9 + k4];
            float4 wq[8];
            const int wc = k4 ^ (cg & 7);
            #pragma unroll
            for (int j = 0; j < 8; ++j)
                wq[j] = Ws[(cg * 8 + j) * 9 + wc];
            #pragma unroll
            for (int rr = 0; rr < 4; ++rr)
                #pragma unroll
                for (int j = 0; j < 8; ++j)
                    acc[rr][j] += xq[rr].x * wq[j].x + xq[rr].y * wq[j].y
                                + xq[rr].z * wq[j].z + xq[rr].w * wq[j].w;
        }
    }

    const int cb = cg << 3;
    float4 b0 = ((const float4*)bias)[cg * 2];
    float4 b1 = ((const float4*)bias)[cg * 2 + 1];
    #pragma unroll
    for (int r = 0; r < 4; ++r) {
        acc[r][0] += b0.x; acc[r][1] += b0.y; acc[r][2] += b0.z; acc[r][3] += b0.w;
        acc[r][4] += b1.x; acc[r][5] += b1.y; acc[r][6] += b1.z; acc[r][7] += b1.w;
    }

    const float es = expf(scale_log[0]);

    #pragma unroll
    for (int r = 0; r < 4; ++r) {
        float sq = 0.f;
        #pragma unroll
        for (int j = 0; j < 8; ++j) sq += acc[r][j] * acc[r][j];
        if (cg == 0) sq -= acc[r][0] * acc[r][0];   // exclude time channel
        #pragma unroll
        for (int m = 1; m < 16; m <<= 1) sq += __shfl_xor(sq, m, 16);
        float y0   = __shfl(acc[r][0], 0, 16);
        float time = es / (1.f + expf(-y0)) + 1.1f;
        float ss   = sqrtf((time * time - 1.f) / (sq + 1e-8f));
        float4 o0, o1;
        o0.x = (cg == 0) ? time : acc[r][0] * ss;
        o0.y = acc[r][1] * ss; o0.z = acc[r][2] * ss; o0.w = acc[r][3] * ss;
        o1.x = acc[r][4] * ss; o1.y = acc[r][5] * ss;
        o1.z = acc[r][6] * ss; o1.w = acc[r][7] * ss;
        int grow = row0 + (rg << 2) + r;
        if (grow < N) {
            float4* ph = (float4*)(Xh + (size_t)grow * 128 + cb);
            ph[0] = o0; ph[1] = o1;
        }
    }
}

// ---------------- CSR build -------------------------------------------------
__global__ __launch_bounds__(256) void count_both_kernel(
    const int* __restrict__ edges, const int* __restrict__ vertex,
    int* __restrict__ hist_e, int* __restrict__ hist_v, int n)
{
    int i = blockIdx.x * 256 + threadIdx.x;
    if (i < n) {
        atomicAdd(&hist_e[edges[i]], 1);
        atomicAdd(&hist_v[vertex[i]], 1);
    }
}

// --- hierarchical exclusive scan ---
__global__ __launch_bounds__(256) void scan_partial_kernel(
    const int* __restrict__ counts, int* __restrict__ offs,
    int* __restrict__ bsums, int n)
{
    __shared__ int buf[256];
    const int b = blockIdx.x, tid = threadIdx.x;
    const int i0 = b * 1024 + tid * 4;
    int c0 = (i0 + 0 < n) ? counts[i0 + 0] : 0;
    int c1 = (i0 + 1 < n) ? counts[i0 + 1] : 0;
    int c2 = (i0 + 2 < n) ? counts[i0 + 2] : 0;
    int c3 = (i0 + 3 < n) ? counts[i0 + 3] : 0;
    int s = c0 + c1 + c2 + c3;
    buf[tid] = s;
    __syncthreads();
    #pragma unroll
    for (int off = 1; off < 256; off <<= 1) {
        int v = (tid >= off) ? buf[tid - off] : 0;
        __syncthreads();
        buf[tid] += v;
        __syncthreads();
    }
    int ex = buf[tid] - s;
    if (i0 + 0 < n) offs[i0 + 0] = ex;
    if (i0 + 1 < n) offs[i0 + 1] = ex + c0;
    if (i0 + 2 < n) offs[i0 + 2] = ex + c0 + c1;
    if (i0 + 3 < n) offs[i0 + 3] = ex + c0 + c1 + c2;
    if (tid == 255) bsums[b] = buf[255];
}

__global__ __launch_bounds__(256) void scan_bsums_kernel(
    int* __restrict__ bsums, int nb)   // nb <= 256
{
    __shared__ int buf[256];
    const int tid = threadIdx.x;
    int v = (tid < nb) ? bsums[tid] : 0;
    buf[tid] = v;
    __syncthreads();
    #pragma unroll
    for (int off = 1; off < 256; off <<= 1) {
        int u = (tid >= off) ? buf[tid - off] : 0;
        __syncthreads();
        buf[tid] += u;
        __syncthreads();
    }
    if (tid < nb) bsums[tid] = buf[tid] - v;   // exclusive
}

__global__ __launch_bounds__(256) void scan_add_kernel(
    int* __restrict__ offs, const int* __restrict__ bsums, int n, int total)
{
    const int b = blockIdx.x, tid = threadIdx.x;
    const int add = bsums[b];
    const int i0 = b * 1024 + tid * 4;
    if (add != 0) {
        if (i0 + 0 < n) offs[i0 + 0] += add;
        if (i0 + 1 < n) offs[i0 + 1] += add;
        if (i0 + 2 < n) offs[i0 + 2] += add;
        if (i0 + 3 < n) offs[i0 + 3] += add;
    }
    if (b == 0 && tid == 0) offs[n] = total;   // sum of counts == nnz
}

// placement, cursor-direct: cur_* pre-loaded with offs (d2d copy), so the
// atomicAdd result IS the absolute output slot.
__global__ __launch_bounds__(256) void fill_both_kernel(
    const int* __restrict__ edges, const int* __restrict__ vertex,
    const int* __restrict__ types,
    int* __restrict__ cur_e, int* __restrict__ vals_e,
    int* __restrict__ cur_v, int* __restrict__ segs_v, int n)
{
    int i = blockIdx.x * 256 + threadIdx.x;
    if (i < n) {
        int s = edges[i];
        int v = vertex[i];
        int pe = atomicAdd(&cur_e[s], 1);
        vals_e[pe] = v | (types[i] << 17);
        int pv = atomicAdd(&cur_v[v], 1);
        segs_v[pv] = s;
    }
}

// ---------------- Kernel 2: Xe[s] = sum_e (Xh[vertex[e]] - emb[ty[e]]) ------
// 1 wave/segment; half-wave owns one row (32 lanes x float4), 2 edges/iter.
__global__ __launch_bounds__(256) void edge_gather_kernel(
    const float* __restrict__ Xh, const float* __restrict__ emb,
    const int* __restrict__ offs, const int* __restrict__ vals,
    float* __restrict__ Xe, int nsegs)
{
    int seg = blockIdx.x * 4 + (threadIdx.x >> 6);
    if (seg >= nsegs) return;
    const int lane = threadIdx.x & 63;
    const int h = lane >> 5, l5 = lane & 31;
    const int beg = offs[seg], end = offs[seg + 1];
    float4 acc = make_float4(0.f, 0.f, 0.f, 0.f);
    for (int e = beg + h; e < end; e += 2) {
        int p  = vals[e];
        int v  = p & 0x1FFFF, ty = p >> 17;
        float4 a = ((const float4*)Xh)[(size_t)v * 32 + l5];
        float4 m = ((const float4*)emb)[ty * 32 + l5];
        acc.x += a.x - m.x; acc.y += a.y - m.y;
        acc.z += a.z - m.z; acc.w += a.w - m.w;
    }
    acc.x += __shfl_xor(acc.x, 32);
    acc.y += __shfl_xor(acc.y, 32);
    acc.z += __shfl_xor(acc.z, 32);
    acc.w += __shfl_xor(acc.w, 32);
    if (h == 0) ((float4*)Xe)[(size_t)seg * 32 + l5] = acc;
}

// ---------------- Kernel 3: out[v] = Xh[v] + eps * sum_e Xe[seg[e]] ---------
__global__ __launch_bounds__(256) void vertex_gather_kernel(
    const float* __restrict__ Xh, const float* __restrict__ Xe,
    const int* __restrict__ offs, const int* __restrict__ segs,
    const float* __restrict__ eps, float* __restrict__ out, int N)
{
    int v = blockIdx.x * 4 + (threadIdx.x >> 6);
    if (v >= N) return;
    const int lane = threadIdx.x & 63;
    const int h = lane >> 5, l5 = lane & 31;
    const int beg = offs[v], end = offs[v + 1];
    float4 acc = make_float4(0.f, 0.f, 0.f, 0.f);
    for (int e = beg + h; e < end; e += 2) {
        int s = segs[e];
        float4 a = ((const float4*)Xe)[(size_t)s * 32 + l5];
        acc.x += a.x; acc.y += a.y; acc.z += a.z; acc.w += a.w;
    }
    acc.x += __shfl_xor(acc.x, 32);
    acc.y += __shfl_xor(acc.y, 32);
    acc.z += __shfl_xor(acc.z, 32);
    acc.w += __shfl_xor(acc.w, 32);
    if (h == 0) {
        float ep = eps[0];
        float4 xh = ((const float4*)Xh)[(size_t)v * 32 + l5];
        float4 o;
        o.x = xh.x + ep * acc.x; o.y = xh.y + ep * acc.y;
        o.z = xh.z + ep * acc.z; o.w = xh.w + ep * acc.w;
        ((float4*)out)[(size_t)v * 32 + l5] = o;
    }
}

extern "C" void kernel_launch(void* const* d_in, const int* in_sizes, int n_in,
                              void* d_out, int out_size, void* d_ws, size_t ws_size,
                              hipStream_t stream) {
    const float* X         = (const float*)d_in[0];
    const float* emb_ty    = (const float*)d_in[1];
    const float* W         = (const float*)d_in[2];
    const float* bias      = (const float*)d_in[3];
    const float* scale_log = (const float*)d_in[4];
    const float* eps       = (const float*)d_in[5];
    const int*   vertex    = (const int*)d_in[6];
    const int*   edges     = (const int*)d_in[7];
    const int*   type_ids  = (const int*)d_in[8];

    const int N   = in_sizes[0] / 128;   // 100000
    const int nnz = in_sizes[6];         // 1000000
    const int E   = E_SEGS;              // 20000

    // ---- workspace layout (~71 MB total) ----
    float* Xh = (float*)d_ws;                       // N*128 floats (51.2 MB)
    float* Xe = Xh + (size_t)N * 128;               // E*128 floats (10.24 MB)
    int* ip      = (int*)(Xe + (size_t)E * 128);
    int* offs_e  = ip;              ip += E + 1;    // 20001
    int* offs_v  = ip;              ip += N + 1;    // 100001
    int* hist_e  = ip;              ip += E;        // \ contiguous zero region
    int* hist_v  = ip;              ip += N;        // /
    int* cur_e   = ip;              ip += E;
    int* cur_v   = ip;              ip += N;
    int* bsum_e  = ip;              ip += 256;
    int* bsum_v  = ip;              ip += 256;
    int* vals_e  = ip;              ip += nnz;      // 1M: vertex|type<<17
    int* segs_v  = ip;              ip += nnz;      // 1M: segment id

    hipMemsetAsync(hist_e, 0, (size_t)(E + N) * sizeof(int), stream);

    float* out = (float*)d_out;
    const int blocks_nnz = (nnz + 255) / 256;
    const int nb_e = (E + 1023) / 1024;   // 20
    const int nb_v = (N + 1023) / 1024;   // 98

    // 1) histograms
    count_both_kernel<<<blocks_nnz, 256, 0, stream>>>(
        edges, vertex, hist_e, hist_v, nnz);

    // 2) hierarchical exclusive scans
    scan_partial_kernel<<<nb_e, 256, 0, stream>>>(hist_e, offs_e, bsum_e, E);
    scan_partial_kernel<<<nb_v, 256, 0, stream>>>(hist_v, offs_v, bsum_v, N);
    scan_bsums_kernel<<<1, 256, 0, stream>>>(bsum_e, nb_e);
    scan_bsums_kernel<<<1, 256, 0, stream>>>(bsum_v, nb_v);
    scan_add_kernel<<<nb_e, 256, 0, stream>>>(offs_e, bsum_e, E, nnz);
    scan_add_kernel<<<nb_v, 256, 0, stream>>>(offs_v, bsum_v, N, nnz);

    // 3) cursors = copy of offs, then cursor-direct placement
    hipMemcpyAsync(cur_e, offs_e, (size_t)E * sizeof(int),
                   hipMemcpyDeviceToDevice, stream);
    hipMemcpyAsync(cur_v, offs_v, (size_t)N * sizeof(int),
                   hipMemcpyDeviceToDevice, stream);
    fill_both_kernel<<<blocks_nnz, 256, 0, stream>>>(
        edges, vertex, type_ids, cur_e, vals_e, cur_v, segs_v, nnz);

    // 4) Xh = lorentz(X W^T + b)
    lorentz_gemm_kernel<<<(N + 63) / 64, 256, 0, stream>>>(
        X, W, bias, scale_log, Xh, N);

    // 5) Xe = segsum(Xh[vertex]-emb[ty]) over edge segments
    edge_gather_kernel<<<(E + 3) / 4, 256, 0, stream>>>(
        Xh, emb_ty, offs_e, vals_e, Xe, E);

    // 6) out = Xh + eps * segsum(Xe[edges]) over vertices
    vertex_gather_kernel<<<(N + 3) / 4, 256, 0, stream>>>(
        Xh, Xe, offs_v, segs_v, eps, out, N);
}

// Round 9
// 657.163 us; speedup vs baseline: 2.6502x; 2.6502x over previous
//
#include <hip/hip_runtime.h>
#include <hip/hip_bf16.h>

// H2Conv: Xh = lorentz_linear(X W^T + b); Xve = Xh[vertex]-emb[ty];
// Xe = segsum(Xve, edges); Xv = segsum(Xe[edges], vertex); out = eps*Xv + Xh
// N=100000, E=20000, NNZ=1e6, D=128. vertex < 2^17, type < 16.
//
// R9: GEMM = R8 structure (4x8 tile, K-chunked staging, 27.6KB LDS) but
// WITHOUT the min-waves launch_bounds arg. R8's (256,3) made the compiler
// allocate 84 VGPR (< the ~132 this tile needs) -> acc spilled to scratch
// -> 4.17 GB HBM traffic/dispatch -> 1179us. Natural regalloc (R6: 132
// VGPR, zero spill) + 27.6KB LDS -> 3 blocks/CU without any forcing.

#define E_SEGS 20000

// ---------------- Kernel 1: fused GEMM + lorentz epilogue -------------------
// 64 rows/block, 256 threads, K in 4 chunks of 32 floats. Thread tile 4x8.
// LDS: Ws[128][9]f4 (18.4KB, XOR-swizzled) + Xs[64][9]f4 (9.2KB, pad only).
// All LDS reads <=2-way bank conflict (free); writes conflict-free.
__global__ __launch_bounds__(256) void lorentz_gemm_kernel(
    const float* __restrict__ X, const float* __restrict__ W,
    const float* __restrict__ bias, const float* __restrict__ scale_log,
    float* __restrict__ Xh, int N)
{
    __shared__ float4 Ws[128 * 9];
    __shared__ float4 Xs[64 * 9];
    const int t = threadIdx.x;
    const int row0 = blockIdx.x * 64;

    const int rg = t >> 4;           // 0..15 -> rows rg*4..+3
    const int cg = t & 15;           // 0..15 -> cols cg*8..+7
    const int sr = t >> 3;           // staging row base (0..31)
    const int sc = t & 7;            // staging f4 col within chunk

    float acc[4][8];
    #pragma unroll
    for (int r = 0; r < 4; ++r)
        #pragma unroll
        for (int j = 0; j < 8; ++j) acc[r][j] = 0.f;

    for (int ch = 0; ch < 4; ++ch) {
        if (ch) __syncthreads();
        const int kb = ch * 8;       // f4 offset of this K-chunk
        #pragma unroll
        for (int i = 0; i < 4; ++i) {
            int d = sr + i * 32;     // W row 0..127
            Ws[d * 9 + (sc ^ ((d >> 3) & 7))] =
                ((const float4*)W)[(size_t)d * 32 + kb + sc];
        }
        #pragma unroll
        for (int i = 0; i < 2; ++i) {
            int r = sr + i * 32;     // tile row 0..63
            int gr = row0 + r;
            float4 x = make_float4(0.f, 0.f, 0.f, 0.f);
            if (gr < N) x = ((const float4*)X)[(size_t)gr * 32 + kb + sc];
            Xs[r * 9 + sc] = x;
        }
        __syncthreads();

        #pragma unroll
        for (int k4 = 0; k4 < 8; ++k4) {
            float4 xq[4];
            #pragma unroll
            for (int rr = 0; rr < 4; ++rr)
                xq[rr] = Xs[(rg * 4 + rr) * 9 + k4];
            float4 wq[8];
            const int wc = k4 ^ (cg & 7);
            #pragma unroll
            for (int j = 0; j < 8; ++j)
                wq[j] = Ws[(cg * 8 + j) * 9 + wc];
            #pragma unroll
            for (int rr = 0; rr < 4; ++rr)
                #pragma unroll
                for (int j = 0; j < 8; ++j)
                    acc[rr][j] += xq[rr].x * wq[j].x + xq[rr].y * wq[j].y
                                + xq[rr].z * wq[j].z + xq[rr].w * wq[j].w;
        }
    }

    const int cb = cg << 3;
    float4 b0 = ((const float4*)bias)[cg * 2];
    float4 b1 = ((const float4*)bias)[cg * 2 + 1];
    #pragma unroll
    for (int r = 0; r < 4; ++r) {
        acc[r][0] += b0.x; acc[r][1] += b0.y; acc[r][2] += b0.z; acc[r][3] += b0.w;
        acc[r][4] += b1.x; acc[r][5] += b1.y; acc[r][6] += b1.z; acc[r][7] += b1.w;
    }

    const float es = expf(scale_log[0]);

    #pragma unroll
    for (int r = 0; r < 4; ++r) {
        float sq = 0.f;
        #pragma unroll
        for (int j = 0; j < 8; ++j) sq += acc[r][j] * acc[r][j];
        if (cg == 0) sq -= acc[r][0] * acc[r][0];   // exclude time channel
        #pragma unroll
        for (int m = 1; m < 16; m <<= 1) sq += __shfl_xor(sq, m, 16);
        float y0   = __shfl(acc[r][0], 0, 16);
        float time = es / (1.f + expf(-y0)) + 1.1f;
        float ss   = sqrtf((time * time - 1.f) / (sq + 1e-8f));
        float4 o0, o1;
        o0.x = (cg == 0) ? time : acc[r][0] * ss;
        o0.y = acc[r][1] * ss; o0.z = acc[r][2] * ss; o0.w = acc[r][3] * ss;
        o1.x = acc[r][4] * ss; o1.y = acc[r][5] * ss;
        o1.z = acc[r][6] * ss; o1.w = acc[r][7] * ss;
        int grow = row0 + (rg << 2) + r;
        if (grow < N) {
            float4* ph = (float4*)(Xh + (size_t)grow * 128 + cb);
            ph[0] = o0; ph[1] = o1;
        }
    }
}

// ---------------- CSR build -------------------------------------------------
__global__ __launch_bounds__(256) void count_both_kernel(
    const int* __restrict__ edges, const int* __restrict__ vertex,
    int* __restrict__ hist_e, int* __restrict__ hist_v, int n)
{
    int i = blockIdx.x * 256 + threadIdx.x;
    if (i < n) {
        atomicAdd(&hist_e[edges[i]], 1);
        atomicAdd(&hist_v[vertex[i]], 1);
    }
}

// --- hierarchical exclusive scan ---
__global__ __launch_bounds__(256) void scan_partial_kernel(
    const int* __restrict__ counts, int* __restrict__ offs,
    int* __restrict__ bsums, int n)
{
    __shared__ int buf[256];
    const int b = blockIdx.x, tid = threadIdx.x;
    const int i0 = b * 1024 + tid * 4;
    int c0 = (i0 + 0 < n) ? counts[i0 + 0] : 0;
    int c1 = (i0 + 1 < n) ? counts[i0 + 1] : 0;
    int c2 = (i0 + 2 < n) ? counts[i0 + 2] : 0;
    int c3 = (i0 + 3 < n) ? counts[i0 + 3] : 0;
    int s = c0 + c1 + c2 + c3;
    buf[tid] = s;
    __syncthreads();
    #pragma unroll
    for (int off = 1; off < 256; off <<= 1) {
        int v = (tid >= off) ? buf[tid - off] : 0;
        __syncthreads();
        buf[tid] += v;
        __syncthreads();
    }
    int ex = buf[tid] - s;
    if (i0 + 0 < n) offs[i0 + 0] = ex;
    if (i0 + 1 < n) offs[i0 + 1] = ex + c0;
    if (i0 + 2 < n) offs[i0 + 2] = ex + c0 + c1;
    if (i0 + 3 < n) offs[i0 + 3] = ex + c0 + c1 + c2;
    if (tid == 255) bsums[b] = buf[255];
}

__global__ __launch_bounds__(256) void scan_bsums_kernel(
    int* __restrict__ bsums, int nb)   // nb <= 256
{
    __shared__ int buf[256];
    const int tid = threadIdx.x;
    int v = (tid < nb) ? bsums[tid] : 0;
    buf[tid] = v;
    __syncthreads();
    #pragma unroll
    for (int off = 1; off < 256; off <<= 1) {
        int u = (tid >= off) ? buf[tid - off] : 0;
        __syncthreads();
        buf[tid] += u;
        __syncthreads();
    }
    if (tid < nb) bsums[tid] = buf[tid] - v;   // exclusive
}

__global__ __launch_bounds__(256) void scan_add_kernel(
    int* __restrict__ offs, const int* __restrict__ bsums, int n, int total)
{
    const int b = blockIdx.x, tid = threadIdx.x;
    const int add = bsums[b];
    const int i0 = b * 1024 + tid * 4;
    if (add != 0) {
        if (i0 + 0 < n) offs[i0 + 0] += add;
        if (i0 + 1 < n) offs[i0 + 1] += add;
        if (i0 + 2 < n) offs[i0 + 2] += add;
        if (i0 + 3 < n) offs[i0 + 3] += add;
    }
    if (b == 0 && tid == 0) offs[n] = total;   // sum of counts == nnz
}

// placement, cursor-direct: cur_* pre-loaded with offs (d2d copy), so the
// atomicAdd result IS the absolute output slot.
__global__ __launch_bounds__(256) void fill_both_kernel(
    const int* __restrict__ edges, const int* __restrict__ vertex,
    const int* __restrict__ types,
    int* __restrict__ cur_e, int* __restrict__ vals_e,
    int* __restrict__ cur_v, int* __restrict__ segs_v, int n)
{
    int i = blockIdx.x * 256 + threadIdx.x;
    if (i < n) {
        int s = edges[i];
        int v = vertex[i];
        int pe = atomicAdd(&cur_e[s], 1);
        vals_e[pe] = v | (types[i] << 17);
        int pv = atomicAdd(&cur_v[v], 1);
        segs_v[pv] = s;
    }
}

// ---------------- Kernel 2: Xe[s] = sum_e (Xh[vertex[e]] - emb[ty[e]]) ------
// 1 wave/segment; half-wave owns one row (32 lanes x float4), 2 edges/iter.
__global__ __launch_bounds__(256) void edge_gather_kernel(
    const float* __restrict__ Xh, const float* __restrict__ emb,
    const int* __restrict__ offs, const int* __restrict__ vals,
    float* __restrict__ Xe, int nsegs)
{
    int seg = blockIdx.x * 4 + (threadIdx.x >> 6);
    if (seg >= nsegs) return;
    const int lane = threadIdx.x & 63;
    const int h = lane >> 5, l5 = lane & 31;
    const int beg = offs[seg], end = offs[seg + 1];
    float4 acc = make_float4(0.f, 0.f, 0.f, 0.f);
    for (int e = beg + h; e < end; e += 2) {
        int p  = vals[e];
        int v  = p & 0x1FFFF, ty = p >> 17;
        float4 a = ((const float4*)Xh)[(size_t)v * 32 + l5];
        float4 m = ((const float4*)emb)[ty * 32 + l5];
        acc.x += a.x - m.x; acc.y += a.y - m.y;
        acc.z += a.z - m.z; acc.w += a.w - m.w;
    }
    acc.x += __shfl_xor(acc.x, 32);
    acc.y += __shfl_xor(acc.y, 32);
    acc.z += __shfl_xor(acc.z, 32);
    acc.w += __shfl_xor(acc.w, 32);
    if (h == 0) ((float4*)Xe)[(size_t)seg * 32 + l5] = acc;
}

// ---------------- Kernel 3: out[v] = Xh[v] + eps * sum_e Xe[seg[e]] ---------
__global__ __launch_bounds__(256) void vertex_gather_kernel(
    const float* __restrict__ Xh, const float* __restrict__ Xe,
    const int* __restrict__ offs, const int* __restrict__ segs,
    const float* __restrict__ eps, float* __restrict__ out, int N)
{
    int v = blockIdx.x * 4 + (threadIdx.x >> 6);
    if (v >= N) return;
    const int lane = threadIdx.x & 63;
    const int h = lane >> 5, l5 = lane & 31;
    const int beg = offs[v], end = offs[v + 1];
    float4 acc = make_float4(0.f, 0.f, 0.f, 0.f);
    for (int e = beg + h; e < end; e += 2) {
        int s = segs[e];
        float4 a = ((const float4*)Xe)[(size_t)s * 32 + l5];
        acc.x += a.x; acc.y += a.y; acc.z += a.z; acc.w += a.w;
    }
    acc.x += __shfl_xor(acc.x, 32);
    acc.y += __shfl_xor(acc.y, 32);
    acc.z += __shfl_xor(acc.z, 32);
    acc.w += __shfl_xor(acc.w, 32);
    if (h == 0) {
        float ep = eps[0];
        float4 xh = ((const float4*)Xh)[(size_t)v * 32 + l5];
        float4 o;
        o.x = xh.x + ep * acc.x; o.y = xh.y + ep * acc.y;
        o.z = xh.z + ep * acc.z; o.w = xh.w + ep * acc.w;
        ((float4*)out)[(size_t)v * 32 + l5] = o;
    }
}

extern "C" void kernel_launch(void* const* d_in, const int* in_sizes, int n_in,
                              void* d_out, int out_size, void* d_ws, size_t ws_size,
                              hipStream_t stream) {
    const float* X         = (const float*)d_in[0];
    const float* emb_ty    = (const float*)d_in[1];
    const float* W         = (const float*)d_in[2];
    const float* bias      = (const float*)d_in[3];
    const float* scale_log = (const float*)d_in[4];
    const float* eps       = (const float*)d_in[5];
    const int*   vertex    = (const int*)d_in[6];
    const int*   edges     = (const int*)d_in[7];
    const int*   type_ids  = (const int*)d_in[8];

    const int N   = in_sizes[0] / 128;   // 100000
    const int nnz = in_sizes[6];         // 1000000
    const int E   = E_SEGS;              // 20000

    // ---- workspace layout (~71 MB total) ----
    float* Xh = (float*)d_ws;                       // N*128 floats (51.2 MB)
    float* Xe = Xh + (size_t)N * 128;               // E*128 floats (10.24 MB)
    int* ip      = (int*)(Xe + (size_t)E * 128);
    int* offs_e  = ip;              ip += E + 1;    // 20001
    int* offs_v  = ip;              ip += N + 1;    // 100001
    int* hist_e  = ip;              ip += E;        // \ contiguous zero region
    int* hist_v  = ip;              ip += N;        // /
    int* cur_e   = ip;              ip += E;
    int* cur_v   = ip;              ip += N;
    int* bsum_e  = ip;              ip += 256;
    int* bsum_v  = ip;              ip += 256;
    int* vals_e  = ip;              ip += nnz;      // 1M: vertex|type<<17
    int* segs_v  = ip;              ip += nnz;      // 1M: segment id

    hipMemsetAsync(hist_e, 0, (size_t)(E + N) * sizeof(int), stream);

    float* out = (float*)d_out;
    const int blocks_nnz = (nnz + 255) / 256;
    const int nb_e = (E + 1023) / 1024;   // 20
    const int nb_v = (N + 1023) / 1024;   // 98

    // 1) histograms
    count_both_kernel<<<blocks_nnz, 256, 0, stream>>>(
        edges, vertex, hist_e, hist_v, nnz);

    // 2) hierarchical exclusive scans
    scan_partial_kernel<<<nb_e, 256, 0, stream>>>(hist_e, offs_e, bsum_e, E);
    scan_partial_kernel<<<nb_v, 256, 0, stream>>>(hist_v, offs_v, bsum_v, N);
    scan_bsums_kernel<<<1, 256, 0, stream>>>(bsum_e, nb_e);
    scan_bsums_kernel<<<1, 256, 0, stream>>>(bsum_v, nb_v);
    scan_add_kernel<<<nb_e, 256, 0, stream>>>(offs_e, bsum_e, E, nnz);
    scan_add_kernel<<<nb_v, 256, 0, stream>>>(offs_v, bsum_v, N, nnz);

    // 3) cursors = copy of offs, then cursor-direct placement
    hipMemcpyAsync(cur_e, offs_e, (size_t)E * sizeof(int),
                   hipMemcpyDeviceToDevice, stream);
    hipMemcpyAsync(cur_v, offs_v, (size_t)N * sizeof(int),
                   hipMemcpyDeviceToDevice, stream);
    fill_both_kernel<<<blocks_nnz, 256, 0, stream>>>(
        edges, vertex, type_ids, cur_e, vals_e, cur_v, segs_v, nnz);

    // 4) Xh = lorentz(X W^T + b)
    lorentz_gemm_kernel<<<(N + 63) / 64, 256, 0, stream>>>(
        X, W, bias, scale_log, Xh, N);

    // 5) Xe = segsum(Xh[vertex]-emb[ty]) over edge segments
    edge_gather_kernel<<<(E + 3) / 4, 256, 0, stream>>>(
        Xh, emb_ty, offs_e, vals_e, Xe, E);

    // 6) out = Xh + eps * segsum(Xe[edges]) over vertices
    vertex_gather_kernel<<<(N + 3) / 4, 256, 0, stream>>>(
        Xh, Xe, offs_v, segs_v, eps, out, N);
}

// Round 10
// 616.706 us; speedup vs baseline: 2.8240x; 1.0656x over previous
//
#include <hip/hip_runtime.h>
#include <hip/hip_bf16.h>

// H2Conv: Xh = lorentz_linear(X W^T + b); Xve = Xh[vertex]-emb[ty];
// Xe = segsum(Xve, edges); Xv = segsum(Xe[edges], vertex); out = eps*Xv + Xh
// N=100000, E=20000, NNZ=1e6, D=128. vertex < 2^17, type < 16.
//
// R10: fill_both (180us, WRITE_SIZE 127MB = 2M x 64B unmerged scattered 4B
// stores) replaced by 2-level binned placement:
//   passA: LDS-staged coarse bucketing (key>>shift, <=128 buckets) -> P
//          (int2 key,payload) in contiguous per-bucket runs (~256B writes)
//   passB: one block per bucket, cursor-direct atomics into final CSR;
//          destination window ~50KB per CU -> L2 merges -> dense writeback.
// P arrays overlay the Xh region (CSR build completes before GEMM).

#define E_SEGS 20000
#define NBKT_MAX 128
#define CHUNK 4096

// ---------------- Kernel 1: fused GEMM + lorentz epilogue -------------------
// 64 rows/block, 256 threads, K in 4 chunks of 32 floats. Thread tile 4x8.
// LDS: Ws[128][9]f4 (18.4KB, XOR-swizzled) + Xs[64][9]f4 (9.2KB, pad only).
// Natural regalloc (132 VGPR, no spill) — do NOT add min-waves bound (R8!).
__global__ __launch_bounds__(256) void lorentz_gemm_kernel(
    const float* __restrict__ X, const float* __restrict__ W,
    const float* __restrict__ bias, const float* __restrict__ scale_log,
    float* __restrict__ Xh, int N)
{
    __shared__ float4 Ws[128 * 9];
    __shared__ float4 Xs[64 * 9];
    const int t = threadIdx.x;
    const int row0 = blockIdx.x * 64;

    const int rg = t >> 4;
    const int cg = t & 15;
    const int sr = t >> 3;
    const int sc = t & 7;

    float acc[4][8];
    #pragma unroll
    for (int r = 0; r < 4; ++r)
        #pragma unroll
        for (int j = 0; j < 8; ++j) acc[r][j] = 0.f;

    for (int ch = 0; ch < 4; ++ch) {
        if (ch) __syncthreads();
        const int kb = ch * 8;
        #pragma unroll
        for (int i = 0; i < 4; ++i) {
            int d = sr + i * 32;
            Ws[d * 9 + (sc ^ ((d >> 3) & 7))] =
                ((const float4*)W)[(size_t)d * 32 + kb + sc];
        }
        #pragma unroll
        for (int i = 0; i < 2; ++i) {
            int r = sr + i * 32;
            int gr = row0 + r;
            float4 x = make_float4(0.f, 0.f, 0.f, 0.f);
            if (gr < N) x = ((const float4*)X)[(size_t)gr * 32 + kb + sc];
            Xs[r * 9 + sc] = x;
        }
        __syncthreads();

        #pragma unroll
        for (int k4 = 0; k4 < 8; ++k4) {
            float4 xq[4];
            #pragma unroll
            for (int rr = 0; rr < 4; ++rr)
                xq[rr] = Xs[(rg * 4 + rr) * 9 + k4];
            float4 wq[8];
            const int wc = k4 ^ (cg & 7);
            #pragma unroll
            for (int j = 0; j < 8; ++j)
                wq[j] = Ws[(cg * 8 + j) * 9 + wc];
            #pragma unroll
            for (int rr = 0; rr < 4; ++rr)
                #pragma unroll
                for (int j = 0; j < 8; ++j)
                    acc[rr][j] += xq[rr].x * wq[j].x + xq[rr].y * wq[j].y
                                + xq[rr].z * wq[j].z + xq[rr].w * wq[j].w;
        }
    }

    const int cb = cg << 3;
    float4 b0 = ((const float4*)bias)[cg * 2];
    float4 b1 = ((const float4*)bias)[cg * 2 + 1];
    #pragma unroll
    for (int r = 0; r < 4; ++r) {
        acc[r][0] += b0.x; acc[r][1] += b0.y; acc[r][2] += b0.z; acc[r][3] += b0.w;
        acc[r][4] += b1.x; acc[r][5] += b1.y; acc[r][6] += b1.z; acc[r][7] += b1.w;
    }

    const float es = expf(scale_log[0]);

    #pragma unroll
    for (int r = 0; r < 4; ++r) {
        float sq = 0.f;
        #pragma unroll
        for (int j = 0; j < 8; ++j) sq += acc[r][j] * acc[r][j];
        if (cg == 0) sq -= acc[r][0] * acc[r][0];
        #pragma unroll
        for (int m = 1; m < 16; m <<= 1) sq += __shfl_xor(sq, m, 16);
        float y0   = __shfl(acc[r][0], 0, 16);
        float time = es / (1.f + expf(-y0)) + 1.1f;
        float ss   = sqrtf((time * time - 1.f) / (sq + 1e-8f));
        float4 o0, o1;
        o0.x = (cg == 0) ? time : acc[r][0] * ss;
        o0.y = acc[r][1] * ss; o0.z = acc[r][2] * ss; o0.w = acc[r][3] * ss;
        o1.x = acc[r][4] * ss; o1.y = acc[r][5] * ss;
        o1.z = acc[r][6] * ss; o1.w = acc[r][7] * ss;
        int grow = row0 + (rg << 2) + r;
        if (grow < N) {
            float4* ph = (float4*)(Xh + (size_t)grow * 128 + cb);
            ph[0] = o0; ph[1] = o1;
        }
    }
}

// ---------------- CSR build -------------------------------------------------
__global__ __launch_bounds__(256) void count_both_kernel(
    const int* __restrict__ edges, const int* __restrict__ vertex,
    int* __restrict__ hist_e, int* __restrict__ hist_v, int n)
{
    int i = blockIdx.x * 256 + threadIdx.x;
    if (i < n) {
        atomicAdd(&hist_e[edges[i]], 1);
        atomicAdd(&hist_v[vertex[i]], 1);
    }
}

// --- hierarchical exclusive scan ---
__global__ __launch_bounds__(256) void scan_partial_kernel(
    const int* __restrict__ counts, int* __restrict__ offs,
    int* __restrict__ bsums, int n)
{
    __shared__ int buf[256];
    const int b = blockIdx.x, tid = threadIdx.x;
    const int i0 = b * 1024 + tid * 4;
    int c0 = (i0 + 0 < n) ? counts[i0 + 0] : 0;
    int c1 = (i0 + 1 < n) ? counts[i0 + 1] : 0;
    int c2 = (i0 + 2 < n) ? counts[i0 + 2] : 0;
    int c3 = (i0 + 3 < n) ? counts[i0 + 3] : 0;
    int s = c0 + c1 + c2 + c3;
    buf[tid] = s;
    __syncthreads();
    #pragma unroll
    for (int off = 1; off < 256; off <<= 1) {
        int v = (tid >= off) ? buf[tid - off] : 0;
        __syncthreads();
        buf[tid] += v;
        __syncthreads();
    }
    int ex = buf[tid] - s;
    if (i0 + 0 < n) offs[i0 + 0] = ex;
    if (i0 + 1 < n) offs[i0 + 1] = ex + c0;
    if (i0 + 2 < n) offs[i0 + 2] = ex + c0 + c1;
    if (i0 + 3 < n) offs[i0 + 3] = ex + c0 + c1 + c2;
    if (tid == 255) bsums[b] = buf[255];
}

__global__ __launch_bounds__(256) void scan_bsums_kernel(
    int* __restrict__ bsums, int nb)   // nb <= 256
{
    __shared__ int buf[256];
    const int tid = threadIdx.x;
    int v = (tid < nb) ? bsums[tid] : 0;
    buf[tid] = v;
    __syncthreads();
    #pragma unroll
    for (int off = 1; off < 256; off <<= 1) {
        int u = (tid >= off) ? buf[tid - off] : 0;
        __syncthreads();
        buf[tid] += u;
        __syncthreads();
    }
    if (tid < nb) bsums[tid] = buf[tid] - v;   // exclusive
}

__global__ __launch_bounds__(256) void scan_add_kernel(
    int* __restrict__ offs, const int* __restrict__ bsums, int n, int total)
{
    const int b = blockIdx.x, tid = threadIdx.x;
    const int add = bsums[b];
    const int i0 = b * 1024 + tid * 4;
    if (add != 0) {
        if (i0 + 0 < n) offs[i0 + 0] += add;
        if (i0 + 1 < n) offs[i0 + 1] += add;
        if (i0 + 2 < n) offs[i0 + 2] += add;
        if (i0 + 3 < n) offs[i0 + 3] += add;
    }
    if (b == 0 && tid == 0) offs[n] = total;
}

// bucket cursors: bcur[b] = offs[min(b<<shift, nkeys)]
__global__ __launch_bounds__(256) void init_bcur_kernel(
    const int* __restrict__ offs_e, const int* __restrict__ offs_v,
    int* __restrict__ bcur_e, int* __restrict__ bcur_v,
    int shift_e, int ne, int shift_v, int nv)
{
    int b = threadIdx.x;
    if (b < NBKT_MAX) {
        int ke = b << shift_e; if (ke > ne) ke = ne;
        bcur_e[b] = offs_e[ke];
        int kv = b << shift_v; if (kv > nv) kv = nv;
        bcur_v[b] = offs_v[kv];
    }
}

// passA: coarse bucket partition with LDS staging -> P (int2: key, payload)
// mode 0: key=edges[i],  payload=vertex[i]|(types[i]<<17)
// mode 1: key=vertex[i], payload=edges[i]
__global__ __launch_bounds__(256) void bucket_scatter_kernel(
    const int* __restrict__ edges, const int* __restrict__ vertex,
    const int* __restrict__ types, int mode, int shift,
    int* __restrict__ bcur, int2* __restrict__ P, int n)
{
    __shared__ int hist[NBKT_MAX];
    __shared__ int lstart[NBKT_MAX];
    __shared__ int gbase[NBKT_MAX];
    __shared__ int cur2[NBKT_MAX];
    __shared__ int s_tot;
    __shared__ int2 stage[CHUNK];
    const int tid = threadIdx.x;
    const int c0 = blockIdx.x * CHUNK;

    for (int j = tid; j < NBKT_MAX; j += 256) hist[j] = 0;
    __syncthreads();

    int myk[16], myp[16];
    #pragma unroll
    for (int u = 0; u < 16; ++u) {
        int i = c0 + tid + u * 256;
        int k = -1, p = 0;
        if (i < n) {
            if (mode == 0) { k = edges[i];  p = vertex[i] | (types[i] << 17); }
            else           { k = vertex[i]; p = edges[i]; }
        }
        myk[u] = k; myp[u] = p;
        if (k >= 0) atomicAdd(&hist[k >> shift], 1);
    }
    __syncthreads();

    if (tid == 0) {
        int run = 0;
        #pragma unroll 4
        for (int b = 0; b < NBKT_MAX; ++b) { lstart[b] = run; run += hist[b]; }
        s_tot = run;
    }
    __syncthreads();
    if (tid < NBKT_MAX) {
        cur2[tid] = lstart[tid];
        int h = hist[tid];
        gbase[tid] = h ? atomicAdd(&bcur[tid], h) : 0;
    }
    __syncthreads();

    #pragma unroll
    for (int u = 0; u < 16; ++u) {
        int k = myk[u];
        if (k >= 0) {
            int pos = atomicAdd(&cur2[k >> shift], 1);
            stage[pos] = make_int2(k, myp[u]);
        }
    }
    __syncthreads();

    const int tot = s_tot;
    for (int j = tid; j < tot; j += 256) {
        int2 e = stage[j];
        int b = e.x >> shift;
        P[gbase[b] + (j - lstart[b])] = e;     // ~256B contiguous runs
    }
}

// passB: one block per bucket; place payloads via cursor-direct atomics.
// Destination window per block ~= bucket CSR range (~40-50KB) -> L2 merges.
__global__ __launch_bounds__(256) void bucket_place_kernel(
    const int2* __restrict__ P, const int* __restrict__ offs,
    int* __restrict__ cur, int* __restrict__ dst, int shift, int nkeys)
{
    const int b = blockIdx.x;
    int klo = b << shift;
    int khi = klo + (1 << shift); if (khi > nkeys) khi = nkeys;
    const int beg = offs[klo], end = offs[khi];
    for (int j = beg + (int)threadIdx.x; j < end; j += 256) {
        int2 e = P[j];
        int pos = atomicAdd(&cur[e.x], 1);
        dst[pos] = e.y;
    }
}

// ---------------- Kernel 2: Xe[s] = sum_e (Xh[vertex[e]] - emb[ty[e]]) ------
__global__ __launch_bounds__(256) void edge_gather_kernel(
    const float* __restrict__ Xh, const float* __restrict__ emb,
    const int* __restrict__ offs, const int* __restrict__ vals,
    float* __restrict__ Xe, int nsegs)
{
    int seg = blockIdx.x * 4 + (threadIdx.x >> 6);
    if (seg >= nsegs) return;
    const int lane = threadIdx.x & 63;
    const int h = lane >> 5, l5 = lane & 31;
    const int beg = offs[seg], end = offs[seg + 1];
    float4 acc = make_float4(0.f, 0.f, 0.f, 0.f);
    for (int e = beg + h; e < end; e += 2) {
        int p  = vals[e];
        int v  = p & 0x1FFFF, ty = p >> 17;
        float4 a = ((const float4*)Xh)[(size_t)v * 32 + l5];
        float4 m = ((const float4*)emb)[ty * 32 + l5];
        acc.x += a.x - m.x; acc.y += a.y - m.y;
        acc.z += a.z - m.z; acc.w += a.w - m.w;
    }
    acc.x += __shfl_xor(acc.x, 32);
    acc.y += __shfl_xor(acc.y, 32);
    acc.z += __shfl_xor(acc.z, 32);
    acc.w += __shfl_xor(acc.w, 32);
    if (h == 0) ((float4*)Xe)[(size_t)seg * 32 + l5] = acc;
}

// ---------------- Kernel 3: out[v] = Xh[v] + eps * sum_e Xe[seg[e]] ---------
__global__ __launch_bounds__(256) void vertex_gather_kernel(
    const float* __restrict__ Xh, const float* __restrict__ Xe,
    const int* __restrict__ offs, const int* __restrict__ segs,
    const float* __restrict__ eps, float* __restrict__ out, int N)
{
    int v = blockIdx.x * 4 + (threadIdx.x >> 6);
    if (v >= N) return;
    const int lane = threadIdx.x & 63;
    const int h = lane >> 5, l5 = lane & 31;
    const int beg = offs[v], end = offs[v + 1];
    float4 acc = make_float4(0.f, 0.f, 0.f, 0.f);
    for (int e = beg + h; e < end; e += 2) {
        int s = segs[e];
        float4 a = ((const float4*)Xe)[(size_t)s * 32 + l5];
        acc.x += a.x; acc.y += a.y; acc.z += a.z; acc.w += a.w;
    }
    acc.x += __shfl_xor(acc.x, 32);
    acc.y += __shfl_xor(acc.y, 32);
    acc.z += __shfl_xor(acc.z, 32);
    acc.w += __shfl_xor(acc.w, 32);
    if (h == 0) {
        float ep = eps[0];
        float4 xh = ((const float4*)Xh)[(size_t)v * 32 + l5];
        float4 o;
        o.x = xh.x + ep * acc.x; o.y = xh.y + ep * acc.y;
        o.z = xh.z + ep * acc.z; o.w = xh.w + ep * acc.w;
        ((float4*)out)[(size_t)v * 32 + l5] = o;
    }
}

extern "C" void kernel_launch(void* const* d_in, const int* in_sizes, int n_in,
                              void* d_out, int out_size, void* d_ws, size_t ws_size,
                              hipStream_t stream) {
    const float* X         = (const float*)d_in[0];
    const float* emb_ty    = (const float*)d_in[1];
    const float* W         = (const float*)d_in[2];
    const float* bias      = (const float*)d_in[3];
    const float* scale_log = (const float*)d_in[4];
    const float* eps       = (const float*)d_in[5];
    const int*   vertex    = (const int*)d_in[6];
    const int*   edges     = (const int*)d_in[7];
    const int*   type_ids  = (const int*)d_in[8];

    const int N   = in_sizes[0] / 128;   // 100000
    const int nnz = in_sizes[6];         // 1000000
    const int E   = E_SEGS;              // 20000

    const int shift_e = 8;                       // 256 keys/bucket
    const int shift_v = 10;                      // 1024 keys/bucket
    const int nb_bkt_e = (E + 255) >> 8;         // 79
    const int nb_bkt_v = (N + 1023) >> 10;       // 98

    // ---- workspace layout (~71 MB total) ----
    float* Xh = (float*)d_ws;                       // N*128 floats (51.2 MB)
    float* Xe = Xh + (size_t)N * 128;               // E*128 floats (10.24 MB)
    int* ip      = (int*)(Xe + (size_t)E * 128);
    int* offs_e  = ip;              ip += E + 1;
    int* offs_v  = ip;              ip += N + 1;
    int* hist_e  = ip;              ip += E;        // \ contiguous zero region
    int* hist_v  = ip;              ip += N;        // /
    int* cur_e   = ip;              ip += E;
    int* cur_v   = ip;              ip += N;
    int* bsum_e  = ip;              ip += 256;
    int* bsum_v  = ip;              ip += 256;
    int* bcur_e  = ip;              ip += NBKT_MAX;
    int* bcur_v  = ip;              ip += NBKT_MAX;
    int* vals_e  = ip;              ip += nnz;      // 1M: vertex|type<<17
    int* segs_v  = ip;              ip += nnz;      // 1M: segment id

    // P arrays overlay the Xh region (16 MB < 51.2 MB); CSR build finishes
    // before the GEMM writes Xh.
    int2* P_e = (int2*)Xh;
    int2* P_v = P_e + nnz;

    hipMemsetAsync(hist_e, 0, (size_t)(E + N) * sizeof(int), stream);

    float* out = (float*)d_out;
    const int blocks_nnz = (nnz + 255) / 256;
    const int blocks_chk = (nnz + CHUNK - 1) / CHUNK;   // 245
    const int nb_e = (E + 1023) / 1024;   // 20
    const int nb_v = (N + 1023) / 1024;   // 98

    // 1) histograms
    count_both_kernel<<<blocks_nnz, 256, 0, stream>>>(
        edges, vertex, hist_e, hist_v, nnz);

    // 2) hierarchical exclusive scans
    scan_partial_kernel<<<nb_e, 256, 0, stream>>>(hist_e, offs_e, bsum_e, E);
    scan_partial_kernel<<<nb_v, 256, 0, stream>>>(hist_v, offs_v, bsum_v, N);
    scan_bsums_kernel<<<1, 256, 0, stream>>>(bsum_e, nb_e);
    scan_bsums_kernel<<<1, 256, 0, stream>>>(bsum_v, nb_v);
    scan_add_kernel<<<nb_e, 256, 0, stream>>>(offs_e, bsum_e, E, nnz);
    scan_add_kernel<<<nb_v, 256, 0, stream>>>(offs_v, bsum_v, N, nnz);

    // 3) binned placement: passA (coarse partition) + passB (narrow window)
    init_bcur_kernel<<<1, 256, 0, stream>>>(
        offs_e, offs_v, bcur_e, bcur_v, shift_e, E, shift_v, N);
    hipMemcpyAsync(cur_e, offs_e, (size_t)E * sizeof(int),
                   hipMemcpyDeviceToDevice, stream);
    hipMemcpyAsync(cur_v, offs_v, (size_t)N * sizeof(int),
                   hipMemcpyDeviceToDevice, stream);
    bucket_scatter_kernel<<<blocks_chk, 256, 0, stream>>>(
        edges, vertex, type_ids, 0, shift_e, bcur_e, P_e, nnz);
    bucket_scatter_kernel<<<blocks_chk, 256, 0, stream>>>(
        edges, vertex, type_ids, 1, shift_v, bcur_v, P_v, nnz);
    bucket_place_kernel<<<nb_bkt_e, 256, 0, stream>>>(
        P_e, offs_e, cur_e, vals_e, shift_e, E);
    bucket_place_kernel<<<nb_bkt_v, 256, 0, stream>>>(
        P_v, offs_v, cur_v, segs_v, shift_v, N);

    // 4) Xh = lorentz(X W^T + b)   (overwrites the P overlay — after passB)
    lorentz_gemm_kernel<<<(N + 63) / 64, 256, 0, stream>>>(
        X, W, bias, scale_log, Xh, N);

    // 5) Xe = segsum(Xh[vertex]-emb[ty]) over edge segments
    edge_gather_kernel<<<(E + 3) / 4, 256, 0, stream>>>(
        Xh, emb_ty, offs_e, vals_e, Xe, E);

    // 6) out = Xh + eps * segsum(Xe[edges]) over vertices
    vertex_gather_kernel<<<(N + 3) / 4, 256, 0, stream>>>(
        Xh, Xe, offs_v, segs_v, eps, out, N);
}